// Round 6
// baseline (43.828 us; speedup 1.0000x reference)
//
#include <hip/hip_runtime.h>
#include <math.h>

#define N_ATOMS 4096
#define CUTOFF2 25.0f
#define NBLK    1024
#define BS      256
#define IPB     4                    // i atoms per block; 1 wave (64 lanes) per i
#define CHUNK   512                  // j atoms staged per chunk (24 KB LDS)
#define NCHUNK  (N_ATOMS / CHUNK)    // 8
#define LOG2E   1.4426950408889634f
#define LN2     0.6931471805599453f

__device__ __forceinline__ float pow20f(float t) {
    float t2 = t * t;
    float t4 = t2 * t2;
    float t8 = t4 * t4;
    float t16 = t8 * t8;
    return t16 * t4;
}

// SoA packed params:
//   q0 = {x, y, z, re_inv}
//   q1 = {c1b=beta*log2e, la, fe, Bof=B/fe}   (exp arg = fma(-x, c1b, c1b))
//   q2 = {c1a=alpha*log2e, ka, A, 0}
__global__ __launch_bounds__(256) void pack_kernel(
    const float* __restrict__ coords, const float* __restrict__ params,
    float4* __restrict__ q0g, float4* __restrict__ q1g, float4* __restrict__ q2g,
    int* __restrict__ done_ctr)
{
    if (blockIdx.x == 0 && threadIdx.x == 0) *done_ctr = 0;
    const int a = blockIdx.x * 256 + threadIdx.x;
    const float* p = params + 22 * a;
    const float fe = p[1];
    q0g[a] = { coords[3*a], coords[3*a+1], coords[3*a+2], __builtin_amdgcn_rcpf(p[0]) };
    q1g[a] = { p[5] * LOG2E, p[9], fe, p[7] * __builtin_amdgcn_rcpf(fe) };
    q2g[a] = { p[4] * LOG2E, p[8], p[6], 0.0f };
}

// 1024 blocks x 256 threads. Wave w owns i = bid*4+w; its 64 lanes split the j axis.
// 8 staged chunks of 512 j; register-prefetch next chunk before consuming current.
__global__ __launch_bounds__(256) void eam_fused_kernel(
    const float* __restrict__ params,
    const float4* __restrict__ q0g, const float4* __restrict__ q1g,
    const float4* __restrict__ q2g,
    float* __restrict__ partials, int* __restrict__ done_ctr,
    float* __restrict__ out)
{
    __shared__ float4 sq0[CHUNK], sq1[CHUNK], sq2[CHUNK];   // 24 KB
    __shared__ float sF[IPB], sE[IPB], sR[4];
    __shared__ int sLast;

    const int tid  = threadIdx.x;
    const int w    = tid >> 6;        // 0..3: which i
    const int lane = tid & 63;
    const int i    = blockIdx.x * IPB + w;

    const float4 pi0 = q0g[i];
    const float4 pi1 = q1g[i];
    const float4 pi2 = q2g[i];
    const float xi = pi0.x, yi = pi0.y, zi = pi0.z, re_inv_i = pi0.w;
    const float c1b_i = pi1.x, la_i = pi1.y, fe_i = pi1.z, Bof_i = pi1.w;
    const float c1a_i = pi2.x, ka_i = pi2.y, A_i = pi2.z;

    // prefetch chunk 0 into registers
    float4 p0a = q0g[tid], p0b = q0g[tid + 256];
    float4 p1a = q1g[tid], p1b = q1g[tid + 256];
    float4 p2a = q2g[tid], p2b = q2g[tid + 256];

    float rho = 0.0f;
    float e   = 0.0f;

    for (int c = 0; c < NCHUNK; ++c) {
        __syncthreads();   // previous chunk fully consumed
        sq0[tid] = p0a; sq0[tid + 256] = p0b;
        sq1[tid] = p1a; sq1[tid + 256] = p1b;
        sq2[tid] = p2a; sq2[tid + 256] = p2b;
        __syncthreads();

        if (c + 1 < NCHUNK) {   // issue next-chunk loads; latency hides under compute
            const int nb = (c + 1) * CHUNK;
            p0a = q0g[nb + tid]; p0b = q0g[nb + tid + 256];
            p1a = q1g[nb + tid]; p1b = q1g[nb + tid + 256];
            p2a = q2g[nb + tid]; p2b = q2g[nb + tid + 256];
        }

        #pragma unroll
        for (int k = 0; k < CHUNK / 64; ++k) {
            const int jj = k * 64 + lane;
            const int j  = c * CHUNK + jj;
            const float4 q0 = sq0[jj];
            const float4 q1 = sq1[jj];
            const float dx = q0.x - xi;
            const float dy = q0.y - yi;
            const float dz = q0.z - zi;
            const float r2 = fmaf(dx, dx, fmaf(dy, dy, dz * dz));
            const float r  = __builtin_amdgcn_sqrtf(r2);
            const float x  = r * q0.w;
            const float ej = __builtin_amdgcn_exp2f(fmaf(-x, q1.x, q1.x));
            const float dj = __builtin_amdgcn_rcpf(1.0f + pow20f(x - q1.y));
            const float frj = q1.z * ej * dj;
            rho += (j == i) ? 0.0f : frj;

            if (r2 <= CUTOFF2 && i < j) {   // each unordered pair exactly once
                const float4 q2 = sq2[jj];
                const float xr  = r * re_inv_i;
                const float ei  = __builtin_amdgcn_exp2f(fmaf(-xr, c1b_i, c1b_i));
                const float di  = __builtin_amdgcn_rcpf(1.0f + pow20f(xr - la_i));
                const float fri = fe_i * ei * di;
                const float ph_i = A_i * __builtin_amdgcn_exp2f(fmaf(-xr, c1a_i, c1a_i))
                                       * __builtin_amdgcn_rcpf(1.0f + pow20f(xr - ka_i))
                                 - Bof_i * fri;
                const float ph_j = q2.z * __builtin_amdgcn_exp2f(fmaf(-x, q2.x, q2.x))
                                        * __builtin_amdgcn_rcpf(1.0f + pow20f(x - q2.y))
                                 - q1.w * frj;
                // frj/fri*ph_i + fri/frj*ph_j = (frj^2*ph_i + fri^2*ph_j)/(fri*frj)
                e += 0.5f * fmaf(frj * frj, ph_i, fri * fri * ph_j)
                          * __builtin_amdgcn_rcpf(fri * frj);
            }
        }
    }

    // wave-level reductions: rho (per-i) and e land in lane 0 of each wave
    #pragma unroll
    for (int off = 32; off > 0; off >>= 1) {
        rho += __shfl_down(rho, off, 64);
        e   += __shfl_down(e,   off, 64);
    }

    if (lane == 0) {   // embedding F(rho) for this wave's i
        const float* p = params + 22 * i;
        float F;
        if (rho < p[20]) {
            const float xn = rho / p[20] - 1.0f;
            F = p[10] + xn * (p[11] + xn * (p[12] + xn * p[13]));
        } else if (rho < p[21]) {
            const float xe = rho / p[2] - 1.0f;
            F = p[14] + xe * (p[15] + xe * (p[16] + xe * p[17]));
        } else {
            const float l2 = __builtin_amdgcn_logf(rho / p[3]);   // log2(rho/rho_s)
            const float t  = __builtin_amdgcn_exp2f(p[18] * l2);
            const float lt = p[18] * l2 * LN2;                    // ln(t)
            F = p[19] * (1.0f - lt) * t;
        }
        sF[w] = F;
        sE[w] = e;
    }
    __syncthreads();

    if (tid == 0) {
        float part = (sF[0] + sF[1]) + (sF[2] + sF[3])
                   + (sE[0] + sE[1]) + (sE[2] + sE[3]);
        partials[blockIdx.x] = part;
        // release: partial visible device-wide before counter increment
        int prev = __hip_atomic_fetch_add(done_ctr, 1, __ATOMIC_ACQ_REL,
                                          __HIP_MEMORY_SCOPE_AGENT);
        sLast = (prev == NBLK - 1);
    }
    __syncthreads();

    if (sLast) {   // last-arriving block: all partials visible (acquire above)
        float acc = (partials[tid]       + partials[tid + 256])
                  + (partials[tid + 512] + partials[tid + 768]);
        #pragma unroll
        for (int off = 32; off > 0; off >>= 1) acc += __shfl_down(acc, off, 64);
        if ((tid & 63) == 0) sR[tid >> 6] = acc;
        __syncthreads();
        if (tid == 0) out[0] = (sR[0] + sR[1]) + (sR[2] + sR[3]);
    }
}

extern "C" void kernel_launch(void* const* d_in, const int* in_sizes, int n_in,
                              void* d_out, int out_size, void* d_ws, size_t ws_size,
                              hipStream_t stream) {
    const float* coords = (const float*)d_in[0];   // [4096][3]
    const float* params = (const float*)d_in[1];   // [4096][22]
    float* out = (float*)d_out;

    float* partials = (float*)d_ws;                           // [1024]
    int*   done_ctr = (int*)((float*)d_ws + NBLK);            // [1]
    float4* q0g = (float4*)((float*)d_ws + NBLK + 256);       // [4096] each, 16B-aligned
    float4* q1g = q0g + N_ATOMS;
    float4* q2g = q1g + N_ATOMS;

    pack_kernel<<<N_ATOMS / 256, 256, 0, stream>>>(coords, params, q0g, q1g, q2g, done_ctr);
    eam_fused_kernel<<<NBLK, BS, 0, stream>>>(params, q0g, q1g, q2g, partials, done_ctr, out);
}